// Round 7
// baseline (1093.213 us; speedup 1.0000x reference)
//
#include <hip/hip_runtime.h>
#include <hip/hip_fp16.h>

constexpr int NU = 150000;
constexpr int NR = 150000;
constexpr int Hc = 64;
constexpr int UF = 58;
constexpr int RF = 128;
constexpr long EE = 2000000;
constexpr long ELc = 500000;
constexpr int NTOT = NU + NR;            // combined ids: [0,NR)=recipes, [NR,NTOT)=users
constexpr int BKT = 256;                 // nodes per bucket
constexpr int NB_R = (NR + BKT - 1) / BKT;   // 586
constexpr int NB_U = (NU + BKT - 1) / BKT;   // 586
constexpr int NBKT = NB_R + NB_U;            // 1172
constexpr int CHUNK = 4096;
constexpr int NCHUNK = (int)((EE + CHUNK - 1) / CHUNK);  // 489
constexpr int GBS = (NU + 3) / 4;        // gather blocks per side (4 rows/block) = 37500

__device__ inline float rdlane(float v, int l) {
    return __uint_as_float(__builtin_amdgcn_readlane(__float_as_uint(v), l));
}

// ---- weight pre-transpose: d[k*64+o] = s[o*F+k] (10 small matrices) ----
struct TP { const float* s; float* d; int F; };
struct TP10 { TP m[10]; };
__global__ void transpose_kernel(TP10 p) {
    TP t = p.m[blockIdx.x];
    for (int idx = threadIdx.x; idx < t.F * Hc; idx += blockDim.x) {
        int k = idx >> 6, o = idx & 63;
        t.d[idx] = t.s[o * t.F + k];
    }
}

// ---- CSR build, pass 0: per-bucket edge counts (LDS-binned) ----
__global__ void bucket_count_kernel(const int* __restrict__ ei, int* __restrict__ bcnt) {
    __shared__ int lc[NBKT];
    for (int i = threadIdx.x; i < NBKT; i += 256) lc[i] = 0;
    __syncthreads();
    long e0 = (long)blockIdx.x * CHUNK;
    for (int k = threadIdx.x; k < CHUNK; k += 256) {
        long e = e0 + k;
        if (e < EE) {
            int u = ei[e], r = ei[EE + e];
            atomicAdd(&lc[r >> 8], 1);
            atomicAdd(&lc[NB_R + (u >> 8)], 1);
        }
    }
    __syncthreads();
    for (int i = threadIdx.x; i < NBKT; i += 256)
        if (lc[i]) atomicAdd(&bcnt[i], lc[i]);
}

// ---- pass 1: exclusive scan over NBKT bucket counts (single block) ----
__global__ void bucket_scan_kernel(const int* __restrict__ bcnt, int* __restrict__ bbase,
                                   int* __restrict__ bcur) {
    __shared__ int part[256];
    constexpr int PER = (NBKT + 255) / 256;   // 5
    int t = threadIdx.x;
    int loc[PER];
    int sum = 0;
    for (int j = 0; j < PER; ++j) {
        int i = t * PER + j;
        int v = (i < NBKT) ? bcnt[i] : 0;
        loc[j] = sum;
        sum += v;
    }
    part[t] = sum;
    __syncthreads();
    for (int off = 1; off < 256; off <<= 1) {
        int v = (t >= off) ? part[t - off] : 0;
        __syncthreads();
        part[t] += v;
        __syncthreads();
    }
    int pre = (t == 0) ? 0 : part[t - 1];
    for (int j = 0; j < PER; ++j) {
        int i = t * PER + j;
        if (i < NBKT) {
            int b = pre + loc[j];
            bbase[i] = b;
            bcur[i] = b;
        }
    }
    if (t == 255) bbase[NBKT] = part[255];
}

// ---- pass 2: chunked-reservation record scatter (4B records: local8|src18) ----
__global__ void scatter_records_kernel(const int* __restrict__ ei, int* __restrict__ bcur,
                                       int* __restrict__ rec) {
    __shared__ int lc[NBKT];
    for (int i = threadIdx.x; i < NBKT; i += 256) lc[i] = 0;
    __syncthreads();
    long e0 = (long)blockIdx.x * CHUNK;
    for (int k = threadIdx.x; k < CHUNK; k += 256) {
        long e = e0 + k;
        if (e < EE) {
            int u = ei[e], r = ei[EE + e];
            atomicAdd(&lc[r >> 8], 1);
            atomicAdd(&lc[NB_R + (u >> 8)], 1);
        }
    }
    __syncthreads();
    for (int i = threadIdx.x; i < NBKT; i += 256) {
        int c = lc[i];
        lc[i] = c ? atomicAdd(&bcur[i], c) : 0;   // reserve contiguous range
    }
    __syncthreads();
    for (int k = threadIdx.x; k < CHUNK; k += 256) {
        long e = e0 + k;
        if (e < EE) {
            int u = ei[e], r = ei[EE + e];
            int p1 = atomicAdd(&lc[r >> 8], 1);
            rec[p1] = ((r & 255) << 18) | u;
            int p2 = atomicAdd(&lc[NB_R + (u >> 8)], 1);
            rec[p2] = ((u & 255) << 18) | r;
        }
    }
}

// ---- pass 3: per-bucket counting sort -> adj (+ per-node base/cnt) ----
__global__ void build_adj_kernel(const int* __restrict__ rec, const int* __restrict__ bbase,
                                 int* __restrict__ adj, int* __restrict__ base,
                                 int* __restrict__ cnt) {
    __shared__ int c256[BKT];
    __shared__ int off256[BKT];
    int b = blockIdx.x;
    int s = bbase[b], e = bbase[b + 1];
    int t = threadIdx.x;
    c256[t] = 0;
    __syncthreads();
    for (int k = s + t; k < e; k += 256) atomicAdd(&c256[rec[k] >> 18], 1);
    __syncthreads();
    int v = c256[t];
    off256[t] = v;
    __syncthreads();
    for (int off = 1; off < 256; off <<= 1) {
        int x = (t >= off) ? off256[t - off] : 0;
        __syncthreads();
        off256[t] += x;
        __syncthreads();
    }
    int excl = off256[t] - v;
    bool isU = (b >= NB_R);
    int node = (isU ? (b - NB_R) : b) * BKT + t;
    int lim = isU ? NU : NR;
    if (node < lim) {
        int cid = isU ? (NR + node) : node;
        base[cid] = s + excl;
        cnt[cid] = v;
    }
    c256[t] = s + excl;    // cursors
    __syncthreads();
    for (int k = s + t; k < e; k += 256) {
        int rv = rec[k];
        int p = atomicAdd(&c256[rv >> 18], 1);
        adj[p] = rv & 0x3FFFF;
    }
}

// ---- fused encoder + layer-1 transforms:
//      enc = x@We^T + be + emb[nid] (registers only, never stored)
//      T   = enc@wl^T           (fp16)
//      PRE = enc@wr^T + br      (f32)
template <int F>
__global__ __launch_bounds__(512) void fused_encode_kernel(
        const float* __restrict__ xin, const float* __restrict__ weT,
        const float* __restrict__ be, const float* __restrict__ emb,
        const int* __restrict__ nid,
        const float* __restrict__ wlT, const float* __restrict__ wrT,
        const float* __restrict__ br,
        __half* __restrict__ Tout, float* __restrict__ PRE, int N) {
    __shared__ float we[F * Hc];
    __shared__ float wp[Hc * 128];   // [k][0..63]=wl, [k][64..127]=wr
    for (int idx = threadIdx.x; idx < F * Hc; idx += 512) we[idx] = weT[idx];
    for (int idx = threadIdx.x; idx < Hc * Hc; idx += 512) {
        int k = idx >> 6, o = idx & 63;
        wp[k * 128 + o] = wlT[idx];
        wp[k * 128 + 64 + o] = wrT[idx];
    }
    __syncthreads();
    int t = threadIdx.x & 63;
    int wid = (int)(((long)blockIdx.x * 512 + threadIdx.x) >> 6);
    int nw = (gridDim.x * 512) >> 6;
    float bev = be[t];
    float brv = br[t];
    for (int r = wid; r < N; r += nw) {
        float xv0 = (t < F) ? xin[(long)r * F + t] : 0.0f;
        float xv1 = (F > 64) ? xin[(long)r * F + 64 + t] : 0.0f;
        float enc = bev;
#pragma unroll
        for (int k = 0; k < F; ++k) {
            float s = (k < 64) ? rdlane(xv0, k) : rdlane(xv1, k - 64);
            enc = fmaf(s, we[k * Hc + t], enc);
        }
        enc += emb[(long)nid[r] * Hc + t];
        float tA = 0.0f, tB = brv;
#pragma unroll
        for (int k = 0; k < Hc; ++k) {
            float s = rdlane(enc, k);
            tA = fmaf(s, wp[k * 128 + t], tA);
            tB = fmaf(s, wp[k * 128 + 64 + t], tB);
        }
        Tout[(long)r * Hc + t] = __float2half(tA);
        PRE[(long)r * Hc + t] = tB;
    }
}

// ---- layer-2 dense pair (both relations in one dispatch):
//      TA = in@wl^T (fp16); PREo = in@wr^T + br (f32) ----
__global__ __launch_bounds__(512) void dense2_pair_kernel(
        const float* inU, const float* wlTU, __half* ToutU,
        const float* wrTU, const float* brU, float* PREU,
        const float* inR, const float* wlTR, __half* ToutR,
        const float* wrTR, const float* brR, float* PRER) {
    __shared__ float w[Hc * 128];
    int half = gridDim.x >> 1;
    bool isR = blockIdx.x >= half;
    const float* in  = isR ? inR : inU;
    const float* wlT = isR ? wlTR : wlTU;
    const float* wrT = isR ? wrTR : wrTU;
    const float* br  = isR ? brR : brU;
    __half* Tout = isR ? ToutR : ToutU;
    float* PRE   = isR ? PRER : PREU;
    for (int idx = threadIdx.x; idx < Hc * Hc; idx += 512) {
        int k = idx >> 6, o = idx & 63;
        w[k * 128 + o] = wlT[idx];
        w[k * 128 + 64 + o] = wrT[idx];
    }
    __syncthreads();
    int t = threadIdx.x & 63;
    int wid = (int)((((long)blockIdx.x - (isR ? half : 0)) * 512 + threadIdx.x) >> 6);
    int nw = (half * 512) >> 6;
    float bv = br[t];
    for (int r = wid; r < NU; r += nw) {
        float xv = in[(long)r * Hc + t];
        float accA = 0.0f, accB = bv;
#pragma unroll
        for (int k = 0; k < Hc; ++k) {
            float s = rdlane(xv, k);
            accA = fmaf(s, w[k * 128 + t], accA);
            accB = fmaf(s, w[k * 128 + 64 + t], accB);
        }
        Tout[(long)r * Hc + t] = __float2half(accA);
        PRE[(long)r * Hc + t] = accB;
    }
}

// ---- pure-memory gather pair: io[r] += mean of fp16 T rows; optional relu.
//      Blocks [0,GBS): recipe side; [GBS,2*GBS): user side. ----
__global__ __launch_bounds__(256) void gather_pair_kernel(
        const __half* __restrict__ TA, float* __restrict__ ioA,
        const __half* __restrict__ TB, float* __restrict__ ioB,
        const int* __restrict__ base, const int* __restrict__ cnt,
        const int* __restrict__ adj, int relu) {
    int t = threadIdx.x & 63;
    bool isU = blockIdx.x >= GBS;
    int bid = blockIdx.x - (isU ? GBS : 0);
    int r = (int)(((long)bid * 256 + threadIdx.x) >> 6);
    if (r >= NU) return;
    int noff = isU ? NR : 0;
    const __half* T = isU ? TB : TA;
    float* io = isU ? ioB : ioA;
    int b0 = base[noff + r], c = cnt[noff + r];
    float s0 = 0.0f, s1 = 0.0f, s2 = 0.0f, s3 = 0.0f;
    int j = 0;
    for (; j + 8 <= c; j += 8) {
        int n0 = adj[b0 + j + 0], n1 = adj[b0 + j + 1];
        int n2 = adj[b0 + j + 2], n3 = adj[b0 + j + 3];
        int n4 = adj[b0 + j + 4], n5 = adj[b0 + j + 5];
        int n6 = adj[b0 + j + 6], n7 = adj[b0 + j + 7];
        s0 += __half2float(T[(long)n0 * Hc + t]);
        s1 += __half2float(T[(long)n1 * Hc + t]);
        s2 += __half2float(T[(long)n2 * Hc + t]);
        s3 += __half2float(T[(long)n3 * Hc + t]);
        s0 += __half2float(T[(long)n4 * Hc + t]);
        s1 += __half2float(T[(long)n5 * Hc + t]);
        s2 += __half2float(T[(long)n6 * Hc + t]);
        s3 += __half2float(T[(long)n7 * Hc + t]);
    }
    for (; j < c; ++j) s0 += __half2float(T[(long)adj[b0 + j] * Hc + t]);
    float s = (s0 + s1) + (s2 + s3);
    float o = io[(long)r * Hc + t] + s / fmaxf((float)c, 1.0f);
    if (relu) o = fmaxf(o, 0.0f);
    io[(long)r * Hc + t] = o;
}

// ---- edge dot-product classifier ----
__global__ void edge_dot_kernel(const int* __restrict__ eli,
                                const float* __restrict__ HU2, const float* __restrict__ HR2,
                                float* __restrict__ out) {
    long gid = (long)blockIdx.x * blockDim.x + threadIdx.x;
    long e = gid >> 4;
    int t = (int)(gid & 15);
    if (e >= ELc) return;
    int a = eli[e], b = eli[ELc + e];
    float4 x = *(const float4*)(HU2 + (long)a * Hc + t * 4);
    float4 y = *(const float4*)(HR2 + (long)b * Hc + t * 4);
    float v = x.x * y.x + x.y * y.y + x.z * y.z + x.w * y.w;
    v += __shfl_xor(v, 1);
    v += __shfl_xor(v, 2);
    v += __shfl_xor(v, 4);
    v += __shfl_xor(v, 8);
    if (t == 0) out[e] = v;
}

extern "C" void kernel_launch(void* const* d_in, const int* in_sizes, int n_in,
                              void* d_out, int out_size, void* d_ws, size_t ws_size,
                              hipStream_t stream) {
    const float* x_user   = (const float*)d_in[0];
    const float* x_recipe = (const float*)d_in[1];
    const int*   user_nid = (const int*)d_in[2];
    const int*   rec_nid  = (const int*)d_in[3];
    const int*   edge_index = (const int*)d_in[4];
    const int*   edge_label = (const int*)d_in[5];
    const float* u_w   = (const float*)d_in[6];
    const float* u_b   = (const float*)d_in[7];
    const float* r_w   = (const float*)d_in[8];
    const float* r_b   = (const float*)d_in[9];
    const float* u_emb = (const float*)d_in[10];
    const float* r_emb = (const float*)d_in[11];
    const float* c1ra_wl = (const float*)d_in[12];
    const float* c1ra_bl = (const float*)d_in[13];
    const float* c1ra_wr = (const float*)d_in[14];
    const float* c1rv_wl = (const float*)d_in[15];
    const float* c1rv_bl = (const float*)d_in[16];
    const float* c1rv_wr = (const float*)d_in[17];
    const float* c2ra_wl = (const float*)d_in[18];
    const float* c2ra_bl = (const float*)d_in[19];
    const float* c2ra_wr = (const float*)d_in[20];
    const float* c2rv_wl = (const float*)d_in[21];
    const float* c2rv_bl = (const float*)d_in[22];
    const float* c2rv_wr = (const float*)d_in[23];

    float* ws = (float*)d_ws;
    const long NH = (long)NU * Hc;
    float* B0 = ws;            // PRE_U2 -> HU2
    float* B1 = B0 + NH;       // PRE_R2 -> HR2
    float* B2 = B1 + NH;       // PRE_U -> HU ; rec[] aliases pre-encode
    float* B3 = B2 + NH;       // PRE_R -> HR
    int* cnt   = (int*)(B3 + NH);    // [NTOT]
    int* base  = cnt + NTOT;         // [NTOT]
    int* bcnt  = base + NTOT;        // [NBKT]
    int* bbase = bcnt + NBKT;        // [NBKT+1]
    int* bcur  = bbase + NBKT + 1;   // [NBKT]
    int* adj   = bcur + NBKT;        // [2*EE]
    float* wts = (float*)(adj + 2 * EE);
    float* uwT = wts;                // 58*64
    float* rwT = uwT + UF * Hc;      // 128*64
    float* cT[8];
    cT[0] = rwT + RF * Hc;
    for (int i = 1; i < 8; ++i) cT[i] = cT[i - 1] + Hc * Hc;
    __half* TAh = (__half*)(cT[7] + Hc * Hc);  // fp16 T, user rows
    __half* TBh = TAh + NH;                    // fp16 T, recipe rows
    int* rec = (int*)B2;             // 16MB alias, dead before first B2 write

    // ---- weight transposes (once) ----
    TP10 tp;
    tp.m[0] = {u_w, uwT, UF};
    tp.m[1] = {r_w, rwT, RF};
    const float* srcs[8] = {c1ra_wl, c1ra_wr, c1rv_wl, c1rv_wr,
                            c2ra_wl, c2ra_wr, c2rv_wl, c2rv_wr};
    for (int i = 0; i < 8; ++i) tp.m[2 + i] = {srcs[i], cT[i], Hc};
    transpose_kernel<<<10, 256, 0, stream>>>(tp);

    // ---- CSR build via bucketed counting sort ----
    hipMemsetAsync(bcnt, 0, (size_t)NBKT * sizeof(int), stream);
    bucket_count_kernel<<<NCHUNK, 256, 0, stream>>>(edge_index, bcnt);
    bucket_scan_kernel<<<1, 256, 0, stream>>>(bcnt, bbase, bcur);
    scatter_records_kernel<<<NCHUNK, 256, 0, stream>>>(edge_index, bcur, rec);
    build_adj_kernel<<<NBKT, 256, 0, stream>>>(rec, bbase, adj, base, cnt);

    // ---- fused encoders + layer-1 transforms ----
    // user: TU1 = XU@c1ra_wl (TAh), PRE_U = XU@c1rv_wr + c1rv_bl (B2)
    fused_encode_kernel<UF><<<768, 512, 0, stream>>>(
        x_user, uwT, u_b, u_emb, user_nid, cT[0], cT[3], c1rv_bl, TAh, B2, NU);
    // recipe: TR1 = XR@c1rv_wl (TBh), PRE_R = XR@c1ra_wr + c1ra_bl (B3)
    fused_encode_kernel<RF><<<512, 512, 0, stream>>>(
        x_recipe, rwT, r_b, r_emb, rec_nid, cT[2], cT[1], c1ra_bl, TBh, B3, NR);

    // ---- layer 1 gathers: HR = relu(PRE_R + mean TU1) in B3; HU = relu(PRE_U + mean TR1) in B2
    gather_pair_kernel<<<2 * GBS, 256, 0, stream>>>(TAh, B3, TBh, B2, base, cnt, adj, 1);

    // ---- layer 2 dense pair ----
    // U: TU2 = HU@c2ra_wl (TAh); PRE_U2 = HU@c2rv_wr + c2rv_bl (B0)
    // R: TR2 = HR@c2rv_wl (TBh); PRE_R2 = HR@c2ra_wr + c2ra_bl (B1)
    dense2_pair_kernel<<<1280, 512, 0, stream>>>(
        B2, cT[4], TAh, cT[7], c2rv_bl, B0,
        B3, cT[6], TBh, cT[5], c2ra_bl, B1);

    // ---- layer 2 gathers: HR2 = PRE_R2 + mean TU2 (B1); HU2 = PRE_U2 + mean TR2 (B0)
    gather_pair_kernel<<<2 * GBS, 256, 0, stream>>>(TAh, B1, TBh, B0, base, cnt, adj, 0);

    // ---- classifier: eli[0]=user -> HU2(B0), eli[1]=recipe -> HR2(B1) ----
    edge_dot_kernel<<<(ELc * 16) / 256, 256, 0, stream>>>(edge_label, B0, B1, (float*)d_out);
}

// Round 8
// 800.659 us; speedup vs baseline: 1.3654x; 1.3654x over previous
//
#include <hip/hip_runtime.h>
#include <hip/hip_fp16.h>

constexpr int NU = 150000;
constexpr int NR = 150000;
constexpr int Hc = 64;
constexpr int UF = 58;
constexpr int RF = 128;
constexpr long EE = 2000000;
constexpr long ELc = 500000;
constexpr int NTOT = NU + NR;            // combined ids: [0,NR)=recipes, [NR,NTOT)=users
constexpr int BKT = 256;                 // nodes per bucket
constexpr int NB_R = (NR + BKT - 1) / BKT;   // 586
constexpr int NB_U = (NU + BKT - 1) / BKT;   // 586
constexpr int NBKT = NB_R + NB_U;            // 1172
constexpr int CHUNK = 4096;
constexpr int NCHUNK = (int)((EE + CHUNK - 1) / CHUNK);  // 489
constexpr int GBS = (NU + 3) / 4;        // gather blocks per side (4 rows/block) = 37500

__device__ inline float rdlane(float v, int l) {
    return __uint_as_float(__builtin_amdgcn_readlane(__float_as_uint(v), l));
}

// ---- weight pre-transpose: d[k*64+o] = s[o*F+k] (10 small matrices) ----
struct TP { const float* s; float* d; int F; };
struct TP10 { TP m[10]; };
__global__ void transpose_kernel(TP10 p) {
    TP t = p.m[blockIdx.x];
    for (int idx = threadIdx.x; idx < t.F * Hc; idx += blockDim.x) {
        int k = idx >> 6, o = idx & 63;
        t.d[idx] = t.s[o * t.F + k];
    }
}

// ---- CSR build, pass 0: per-bucket edge counts (LDS-binned) ----
__global__ void bucket_count_kernel(const int* __restrict__ ei, int* __restrict__ bcnt) {
    __shared__ int lc[NBKT];
    for (int i = threadIdx.x; i < NBKT; i += 256) lc[i] = 0;
    __syncthreads();
    long e0 = (long)blockIdx.x * CHUNK;
    for (int k = threadIdx.x; k < CHUNK; k += 256) {
        long e = e0 + k;
        if (e < EE) {
            int u = ei[e], r = ei[EE + e];
            atomicAdd(&lc[r >> 8], 1);
            atomicAdd(&lc[NB_R + (u >> 8)], 1);
        }
    }
    __syncthreads();
    for (int i = threadIdx.x; i < NBKT; i += 256)
        if (lc[i]) atomicAdd(&bcnt[i], lc[i]);
}

// ---- pass 1: exclusive scan over NBKT bucket counts (single block) ----
__global__ void bucket_scan_kernel(const int* __restrict__ bcnt, int* __restrict__ bbase,
                                   int* __restrict__ bcur) {
    __shared__ int part[256];
    constexpr int PER = (NBKT + 255) / 256;   // 5
    int t = threadIdx.x;
    int loc[PER];
    int sum = 0;
    for (int j = 0; j < PER; ++j) {
        int i = t * PER + j;
        int v = (i < NBKT) ? bcnt[i] : 0;
        loc[j] = sum;
        sum += v;
    }
    part[t] = sum;
    __syncthreads();
    for (int off = 1; off < 256; off <<= 1) {
        int v = (t >= off) ? part[t - off] : 0;
        __syncthreads();
        part[t] += v;
        __syncthreads();
    }
    int pre = (t == 0) ? 0 : part[t - 1];
    for (int j = 0; j < PER; ++j) {
        int i = t * PER + j;
        if (i < NBKT) {
            int b = pre + loc[j];
            bbase[i] = b;
            bcur[i] = b;
        }
    }
    if (t == 255) bbase[NBKT] = part[255];
}

// ---- pass 2: chunked-reservation record scatter (4B records: local8|src18) ----
__global__ void scatter_records_kernel(const int* __restrict__ ei, int* __restrict__ bcur,
                                       int* __restrict__ rec) {
    __shared__ int lc[NBKT];
    for (int i = threadIdx.x; i < NBKT; i += 256) lc[i] = 0;
    __syncthreads();
    long e0 = (long)blockIdx.x * CHUNK;
    for (int k = threadIdx.x; k < CHUNK; k += 256) {
        long e = e0 + k;
        if (e < EE) {
            int u = ei[e], r = ei[EE + e];
            atomicAdd(&lc[r >> 8], 1);
            atomicAdd(&lc[NB_R + (u >> 8)], 1);
        }
    }
    __syncthreads();
    for (int i = threadIdx.x; i < NBKT; i += 256) {
        int c = lc[i];
        lc[i] = c ? atomicAdd(&bcur[i], c) : 0;   // reserve contiguous range
    }
    __syncthreads();
    for (int k = threadIdx.x; k < CHUNK; k += 256) {
        long e = e0 + k;
        if (e < EE) {
            int u = ei[e], r = ei[EE + e];
            int p1 = atomicAdd(&lc[r >> 8], 1);
            rec[p1] = ((r & 255) << 18) | u;
            int p2 = atomicAdd(&lc[NB_R + (u >> 8)], 1);
            rec[p2] = ((u & 255) << 18) | r;
        }
    }
}

// ---- pass 3: per-bucket counting sort -> adj (+ per-node base/cnt) ----
__global__ void build_adj_kernel(const int* __restrict__ rec, const int* __restrict__ bbase,
                                 int* __restrict__ adj, int* __restrict__ base,
                                 int* __restrict__ cnt) {
    __shared__ int c256[BKT];
    __shared__ int off256[BKT];
    int b = blockIdx.x;
    int s = bbase[b], e = bbase[b + 1];
    int t = threadIdx.x;
    c256[t] = 0;
    __syncthreads();
    for (int k = s + t; k < e; k += 256) atomicAdd(&c256[rec[k] >> 18], 1);
    __syncthreads();
    int v = c256[t];
    off256[t] = v;
    __syncthreads();
    for (int off = 1; off < 256; off <<= 1) {
        int x = (t >= off) ? off256[t - off] : 0;
        __syncthreads();
        off256[t] += x;
        __syncthreads();
    }
    int excl = off256[t] - v;
    bool isU = (b >= NB_R);
    int node = (isU ? (b - NB_R) : b) * BKT + t;
    int lim = isU ? NU : NR;
    if (node < lim) {
        int cid = isU ? (NR + node) : node;
        base[cid] = s + excl;
        cnt[cid] = v;
    }
    c256[t] = s + excl;    // cursors
    __syncthreads();
    for (int k = s + t; k < e; k += 256) {
        int rv = rec[k];
        int p = atomicAdd(&c256[rv >> 18], 1);
        adj[p] = rv & 0x3FFFF;
    }
}

// ---- node encoder: LDS weights, readlane broadcast, 4-way split chains ----
template <int F>
__global__ __launch_bounds__(256) void encode_kernel(
        const float* __restrict__ xin, const float* __restrict__ wT,
        const float* __restrict__ b, const float* __restrict__ emb,
        const int* __restrict__ nid, float* __restrict__ out, int N) {
    __shared__ float w[F * Hc];
    for (int idx = threadIdx.x; idx < F * Hc; idx += 256) w[idx] = wT[idx];
    __syncthreads();
    int t = threadIdx.x & 63;
    int wave = (int)((blockIdx.x * blockDim.x + threadIdx.x) >> 6);
    int nwaves = (gridDim.x * blockDim.x) >> 6;
    float bv = b[t];
    for (int r = wave; r < N; r += nwaves) {
        float xv0 = (t < F) ? xin[(long)r * F + t] : 0.0f;
        float xv1 = (F > 64) ? xin[(long)r * F + 64 + t] : 0.0f;
        float a0 = bv, a1 = 0.0f, a2 = 0.0f, a3 = 0.0f;
#pragma unroll
        for (int k = 0; k < F; ++k) {
            float s = (k < 64) ? rdlane(xv0, k) : rdlane(xv1, k - 64);
            float wv = w[k * Hc + t];
            if ((k & 3) == 0)      a0 = fmaf(s, wv, a0);
            else if ((k & 3) == 1) a1 = fmaf(s, wv, a1);
            else if ((k & 3) == 2) a2 = fmaf(s, wv, a2);
            else                   a3 = fmaf(s, wv, a3);
        }
        float acc = (a0 + a1) + (a2 + a3);
        acc += emb[(long)nid[r] * Hc + t];
        out[(long)r * Hc + t] = acc;
    }
}

// ---- dense pair (both relations, one dispatch): T = in@wl^T (fp16);
//      PRE = in@wr^T + br (f32). 2-way split chains per output. ----
__global__ __launch_bounds__(256) void dense2_pair_kernel(
        const float* inU, const float* wlTU, __half* ToutU,
        const float* wrTU, const float* brU, float* PREU,
        const float* inR, const float* wlTR, __half* ToutR,
        const float* wrTR, const float* brR, float* PRER) {
    __shared__ float w[Hc * 128];   // [k][0..63]=wl, [k][64..127]=wr
    int half = gridDim.x >> 1;
    bool isR = blockIdx.x >= half;
    const float* in  = isR ? inR : inU;
    const float* wlT = isR ? wlTR : wlTU;
    const float* wrT = isR ? wrTR : wrTU;
    const float* br  = isR ? brR : brU;
    __half* Tout = isR ? ToutR : ToutU;
    float* PRE   = isR ? PRER : PREU;
    for (int idx = threadIdx.x; idx < Hc * Hc; idx += 256) {
        int k = idx >> 6, o = idx & 63;
        w[k * 128 + o] = wlT[idx];
        w[k * 128 + 64 + o] = wrT[idx];
    }
    __syncthreads();
    int t = threadIdx.x & 63;
    int wid = (int)((((long)blockIdx.x - (isR ? half : 0)) * 256 + threadIdx.x) >> 6);
    int nw = (half * 256) >> 6;
    float bv = br[t];
    for (int r = wid; r < NU; r += nw) {
        float xv = in[(long)r * Hc + t];
        float aA0 = 0.0f, aA1 = 0.0f, aB0 = bv, aB1 = 0.0f;
#pragma unroll
        for (int k = 0; k < Hc; k += 2) {
            float s0 = rdlane(xv, k);
            float s1 = rdlane(xv, k + 1);
            aA0 = fmaf(s0, w[k * 128 + t], aA0);
            aA1 = fmaf(s1, w[(k + 1) * 128 + t], aA1);
            aB0 = fmaf(s0, w[k * 128 + 64 + t], aB0);
            aB1 = fmaf(s1, w[(k + 1) * 128 + 64 + t], aB1);
        }
        Tout[(long)r * Hc + t] = __float2half(aA0 + aA1);
        PRE[(long)r * Hc + t] = aB0 + aB1;
    }
}

// ---- gather pair: io[r] += mean of fp16 T rows; optional relu.
//      Half-waves: lanes [0,32) even neighbors, [32,64) odd; each lane
//      loads a __half2 channel-pair -> one load instr fetches 2 rows. ----
__global__ __launch_bounds__(256) void gather_pair_kernel(
        const __half* __restrict__ TA, float* __restrict__ ioA,
        const __half* __restrict__ TB, float* __restrict__ ioB,
        const int* __restrict__ base, const int* __restrict__ cnt,
        const int* __restrict__ adj, int relu) {
    int l = threadIdx.x & 63;
    int g = l >> 5;        // neighbor parity handled by this half-wave
    int c2 = l & 31;       // channel pair: channels (2*c2, 2*c2+1)
    bool isU = blockIdx.x >= GBS;
    int bid = blockIdx.x - (isU ? GBS : 0);
    int r = (int)(((long)bid * 256 + threadIdx.x) >> 6);
    int noff = isU ? NR : 0;
    const __half* T = isU ? TB : TA;
    float* io = isU ? ioB : ioA;
    int b0 = base[noff + r], c = cnt[noff + r];
    float ax0 = 0.0f, ay0 = 0.0f, ax1 = 0.0f, ay1 = 0.0f;
    int j = 0;
    for (; j + 8 <= c; j += 8) {
        int n0 = adj[b0 + j + g];
        int n1 = adj[b0 + j + 2 + g];
        int n2 = adj[b0 + j + 4 + g];
        int n3 = adj[b0 + j + 6 + g];
        float2 f0 = __half22float2(*(const __half2*)(T + (long)n0 * Hc + 2 * c2));
        float2 f1 = __half22float2(*(const __half2*)(T + (long)n1 * Hc + 2 * c2));
        float2 f2 = __half22float2(*(const __half2*)(T + (long)n2 * Hc + 2 * c2));
        float2 f3 = __half22float2(*(const __half2*)(T + (long)n3 * Hc + 2 * c2));
        ax0 += f0.x + f2.x; ay0 += f0.y + f2.y;
        ax1 += f1.x + f3.x; ay1 += f1.y + f3.y;
    }
    for (; j + 2 <= c; j += 2) {
        int n = adj[b0 + j + g];
        float2 f = __half22float2(*(const __half2*)(T + (long)n * Hc + 2 * c2));
        ax0 += f.x; ay0 += f.y;
    }
    if (j < c && g == 0) {   // odd tail: only even half contributes
        int n = adj[b0 + j];
        float2 f = __half22float2(*(const __half2*)(T + (long)n * Hc + 2 * c2));
        ax0 += f.x; ay0 += f.y;
    }
    float sx = ax0 + ax1, sy = ay0 + ay1;
    sx += __shfl_xor(sx, 32);
    sy += __shfl_xor(sy, 32);
    if (g == 0) {
        float inv = 1.0f / fmaxf((float)c, 1.0f);
        float2 cur = *(float2*)(io + (long)r * Hc + 2 * c2);
        float ox = cur.x + sx * inv;
        float oy = cur.y + sy * inv;
        if (relu) { ox = fmaxf(ox, 0.0f); oy = fmaxf(oy, 0.0f); }
        *(float2*)(io + (long)r * Hc + 2 * c2) = make_float2(ox, oy);
    }
}

// ---- edge dot-product classifier ----
__global__ void edge_dot_kernel(const int* __restrict__ eli,
                                const float* __restrict__ HU2, const float* __restrict__ HR2,
                                float* __restrict__ out) {
    long gid = (long)blockIdx.x * blockDim.x + threadIdx.x;
    long e = gid >> 4;
    int t = (int)(gid & 15);
    if (e >= ELc) return;
    int a = eli[e], b = eli[ELc + e];
    float4 x = *(const float4*)(HU2 + (long)a * Hc + t * 4);
    float4 y = *(const float4*)(HR2 + (long)b * Hc + t * 4);
    float v = x.x * y.x + x.y * y.y + x.z * y.z + x.w * y.w;
    v += __shfl_xor(v, 1);
    v += __shfl_xor(v, 2);
    v += __shfl_xor(v, 4);
    v += __shfl_xor(v, 8);
    if (t == 0) out[e] = v;
}

extern "C" void kernel_launch(void* const* d_in, const int* in_sizes, int n_in,
                              void* d_out, int out_size, void* d_ws, size_t ws_size,
                              hipStream_t stream) {
    const float* x_user   = (const float*)d_in[0];
    const float* x_recipe = (const float*)d_in[1];
    const int*   user_nid = (const int*)d_in[2];
    const int*   rec_nid  = (const int*)d_in[3];
    const int*   edge_index = (const int*)d_in[4];
    const int*   edge_label = (const int*)d_in[5];
    const float* u_w   = (const float*)d_in[6];
    const float* u_b   = (const float*)d_in[7];
    const float* r_w   = (const float*)d_in[8];
    const float* r_b   = (const float*)d_in[9];
    const float* u_emb = (const float*)d_in[10];
    const float* r_emb = (const float*)d_in[11];
    const float* c1ra_wl = (const float*)d_in[12];
    const float* c1ra_bl = (const float*)d_in[13];
    const float* c1ra_wr = (const float*)d_in[14];
    const float* c1rv_wl = (const float*)d_in[15];
    const float* c1rv_bl = (const float*)d_in[16];
    const float* c1rv_wr = (const float*)d_in[17];
    const float* c2ra_wl = (const float*)d_in[18];
    const float* c2ra_bl = (const float*)d_in[19];
    const float* c2ra_wr = (const float*)d_in[20];
    const float* c2rv_wl = (const float*)d_in[21];
    const float* c2rv_bl = (const float*)d_in[22];
    const float* c2rv_wr = (const float*)d_in[23];

    float* ws = (float*)d_ws;
    const long NH = (long)NU * Hc;
    float* B0 = ws;            // XU -> PRE_U2 -> HU2
    float* B1 = B0 + NH;       // XR -> PRE_R2 -> HR2
    float* B2 = B1 + NH;       // rec alias -> PRE_U -> HU
    float* B3 = B2 + NH;       // PRE_R -> HR
    int* cnt   = (int*)(B3 + NH);    // [NTOT]
    int* base  = cnt + NTOT;         // [NTOT]
    int* bcnt  = base + NTOT;        // [NBKT]
    int* bbase = bcnt + NBKT;        // [NBKT+1]
    int* bcur  = bbase + NBKT + 1;   // [NBKT]
    int* adj   = bcur + NBKT;        // [2*EE]
    float* wts = (float*)(adj + 2 * EE);
    float* uwT = wts;                // 58*64
    float* rwT = uwT + UF * Hc;      // 128*64
    float* cT[8];
    cT[0] = rwT + RF * Hc;
    for (int i = 1; i < 8; ++i) cT[i] = cT[i - 1] + Hc * Hc;
    __half* TAh = (__half*)(cT[7] + Hc * Hc);  // fp16 T, user rows
    __half* TBh = TAh + NH;                    // fp16 T, recipe rows
    int* rec = (int*)B2;             // 16MB alias, dead before first B2 write

    // ---- weight transposes (once) ----
    TP10 tp;
    tp.m[0] = {u_w, uwT, UF};
    tp.m[1] = {r_w, rwT, RF};
    const float* srcs[8] = {c1ra_wl, c1ra_wr, c1rv_wl, c1rv_wr,
                            c2ra_wl, c2ra_wr, c2rv_wl, c2rv_wr};
    for (int i = 0; i < 8; ++i) tp.m[2 + i] = {srcs[i], cT[i], Hc};
    transpose_kernel<<<10, 256, 0, stream>>>(tp);

    // ---- CSR build via bucketed counting sort ----
    hipMemsetAsync(bcnt, 0, (size_t)NBKT * sizeof(int), stream);
    bucket_count_kernel<<<NCHUNK, 256, 0, stream>>>(edge_index, bcnt);
    bucket_scan_kernel<<<1, 256, 0, stream>>>(bcnt, bbase, bcur);
    scatter_records_kernel<<<NCHUNK, 256, 0, stream>>>(edge_index, bcur, rec);
    build_adj_kernel<<<NBKT, 256, 0, stream>>>(rec, bbase, adj, base, cnt);

    // ---- encoders: XU -> B0, XR -> B1 ----
    encode_kernel<UF><<<2048, 256, 0, stream>>>(x_user, uwT, u_b, u_emb, user_nid, B0, NU);
    encode_kernel<RF><<<2048, 256, 0, stream>>>(x_recipe, rwT, r_b, r_emb, rec_nid, B1, NR);

    // ---- layer 1 dense pair ----
    // U: TU1 = XU@c1ra_wl (TAh); PRE_U = XU@c1rv_wr + c1rv_bl (B2)
    // R: TR1 = XR@c1rv_wl (TBh); PRE_R = XR@c1ra_wr + c1ra_bl (B3)
    dense2_pair_kernel<<<2048, 256, 0, stream>>>(
        B0, cT[0], TAh, cT[3], c1rv_bl, B2,
        B1, cT[2], TBh, cT[1], c1ra_bl, B3);

    // ---- layer 1 gathers: HR = relu(PRE_R + mean TU1) (B3); HU = relu(PRE_U + mean TR1) (B2)
    gather_pair_kernel<<<2 * GBS, 256, 0, stream>>>(TAh, B3, TBh, B2, base, cnt, adj, 1);

    // ---- layer 2 dense pair ----
    // U: TU2 = HU@c2ra_wl (TAh); PRE_U2 = HU@c2rv_wr + c2rv_bl (B0)
    // R: TR2 = HR@c2rv_wl (TBh); PRE_R2 = HR@c2ra_wr + c2ra_bl (B1)
    dense2_pair_kernel<<<2048, 256, 0, stream>>>(
        B2, cT[4], TAh, cT[7], c2rv_bl, B0,
        B3, cT[6], TBh, cT[5], c2ra_bl, B1);

    // ---- layer 2 gathers: HR2 = PRE_R2 + mean TU2 (B1); HU2 = PRE_U2 + mean TR2 (B0)
    gather_pair_kernel<<<2 * GBS, 256, 0, stream>>>(TAh, B1, TBh, B0, base, cnt, adj, 0);

    // ---- classifier: eli[0]=user -> HU2(B0), eli[1]=recipe -> HR2(B1) ----
    edge_dot_kernel<<<(ELc * 16) / 256, 256, 0, stream>>>(edge_label, B0, B1, (float*)d_out);
}